// Round 16
// baseline (839.037 us; speedup 1.0000x reference)
//
#include <hip/hip_runtime.h>

typedef unsigned short u16;
typedef u16 u16x4 __attribute__((ext_vector_type(4)));
typedef u16 u16x8 __attribute__((ext_vector_type(8)));
typedef __bf16 bf16x8 __attribute__((ext_vector_type(8)));
typedef float f32x4 __attribute__((ext_vector_type(4)));

#define HB   256    // H
#define NND  127    // nodes per tree
#define BT   512    // trees (batch)
#define KE   300    // E
#define KEP  320    // E padded to 32-multiple
#define VV   50000  // vocab
#define QQ   10     // Q

#define AS1 __attribute__((address_space(1)))
#define AS3 __attribute__((address_space(3)))

__device__ __forceinline__ u16 f2bf(float f) {
    unsigned int u = __builtin_bit_cast(unsigned int, f);
    u += 0x7FFFu + ((u >> 16) & 1u);          // RNE
    return (u16)(u >> 16);
}
__device__ __forceinline__ float bf2f(u16 h) {
    unsigned int u = ((unsigned int)h) << 16;
    return __builtin_bit_cast(float, u);
}
__device__ __forceinline__ float sigm(float x) { return 1.f / (1.f + __expf(-x)); }

__device__ __forceinline__ void glds16(const u16* g, u16* l) {
    __builtin_amdgcn_global_load_lds((const AS1 void*)g, (AS3 void*)l, 16, 0, 0);
}

// ---------- merged prep: vocab conv (15625 blks), W (120), U (96), qD (30) ----------
__global__ __launch_bounds__(256) void k_prep(const float* __restrict__ vec,
                                              u16* __restrict__ vb,
                                              const float* __restrict__ W,
                                              const float* __restrict__ U,
                                              const float* __restrict__ q,
                                              const float* __restrict__ D,
                                              u16* __restrict__ Wb,
                                              u16* __restrict__ Ub,
                                              float* __restrict__ qD) {
    int blk = blockIdx.x;
    if (blk < 15625) {                     // vec: VV rows, K=300 -> Kp=320, u16x4 chunks
        long i = (long)blk * 256 + threadIdx.x;   // 4,000,000 chunks exactly
        int r = (int)(i / 80);
        int c = ((int)(i - (long)r * 80)) * 4;
        u16x4 o = {0, 0, 0, 0};
        if (c < KE) {
            f32x4 x = *(const f32x4*)(vec + (long)r * KE + c);
#pragma unroll
            for (int e = 0; e < 4; ++e) o[e] = f2bf(x[e]);
        }
        *(u16x4*)(vb + i * 4) = o;
    } else if (blk < 15745) {              // W: 768 rows, K=300 -> Kp=320 (40 chunks)
        int i = (blk - 15625) * 256 + threadIdx.x;
        int r = i / 40, c = (i - r * 40) * 8;
        const float* s = W + (long)r * KE + c;
        u16x8 o;
#pragma unroll
        for (int e = 0; e < 8; ++e) o[e] = (c + e < KE) ? f2bf(s[e]) : (u16)0;
        *(u16x8*)(Wb + (long)i * 8) = o;
    } else if (blk < 15841) {              // U: 768 rows, K=Kp=256 (32 chunks)
        int i = (blk - 15745) * 256 + threadIdx.x;
        int r = i / 32, c = (i - r * 32) * 8;
        const float* s = U + (long)r * HB + c;
        u16x8 o;
#pragma unroll
        for (int e = 0; e < 8; ++e) o[e] = f2bf(s[e]);
        *(u16x8*)(Ub + (long)i * 8) = o;
    } else {                               // qD[i] over QQ*768
        int i = (blk - 15841) * 256 + threadIdx.x;
        int qi = i / 768, col = i - qi * 768;
        const float* qr = q + qi * HB;
        const float* dr = D + col * HB;
        float s = 0.f;
        for (int k = 0; k < HB; ++k) s += qr[k] * dr[k];
        qD[i] = s;
    }
}

// ---------- bf16 NT GEMM (N=768 fixed): glds16, 128x128 tile, depth-3 counted vmcnt ----------
// Frozen R6 schedule. FUSE: after storing a g tile, last-of-6 finisher per row-block
// runs the 64-parent update for that row-block (device-scope atomic + fences, G16).
template <bool FUSE>
__global__ __launch_bounds__(256) void k_gemm(const u16* A,
                                              const u16* __restrict__ B,
                                              u16* __restrict__ C,
                                              int M, int K,
                                              int map_cnlog2, int map_cstart,
                                              const int* __restrict__ tok,
                                              const int* __restrict__ dep,
                                              const u16* __restrict__ vW,
                                              const float* __restrict__ qD,
                                              const float* __restrict__ bias,
                                              u16* h,
                                              float* __restrict__ out,
                                              int* __restrict__ cnt,
                                              int pnl) {
    __shared__ u16 As[4][128 * 32];
    __shared__ u16 Bs[4][128 * 32];
    const int N = 768;

    // bijective XCD-chunked swizzle (m204)
    int nwg = gridDim.x * gridDim.y;
    int orig = blockIdx.y * gridDim.x + blockIdx.x;
    int qq = nwg >> 3, rr = nwg & 7;
    int xcd = orig & 7, cidx = orig >> 3;
    int wg = (xcd < rr ? xcd * (qq + 1) : rr * (qq + 1) + (xcd - rr) * qq) + cidx;
    int bx = wg % gridDim.x, by = wg / gridDim.x;
    int row0 = by * 128, col0 = bx * 128;

    int t = threadIdx.x, lane = t & 63, w = t >> 6;
    int wr = w >> 1, wc = w & 1;

    int cof = (lane & 3) * 8;            // u16 col offset
    int rin = lane >> 2;                 // 0..15 row within issue
    int ar0 = row0 + w * 32 + rin;
    int ar1 = ar0 + 16;
    auto mapfn = [&](int r) {
        if (r > M - 1) r = M - 1;
        if (map_cnlog2 >= 0) {
            int bt = r >> map_cnlog2;
            int of = r & ((1 << map_cnlog2) - 1);
            r = bt * NND + map_cstart + of;
        }
        return r;
    };
    const u16* aS0 = A + (long)mapfn(ar0) * K + cof;
    const u16* aS1 = A + (long)mapfn(ar1) * K + cof;
    const u16* bS0 = B + (long)(col0 + w * 32 + rin) * K + cof;
    const u16* bS1 = bS0 + 16L * K;
    int dof0 = (w * 32) * 32;
    int dof1 = (w * 32 + 16) * 32;

    f32x4 acc[4][4];
#pragma unroll
    for (int m = 0; m < 4; ++m)
#pragma unroll
        for (int n = 0; n < 4; ++n) acc[m][n] = f32x4{0.f, 0.f, 0.f, 0.f};

    int arl = wr * 64 + (lane & 15);
    int brl = wc * 64 + (lane & 15);
    int kk = (lane >> 4) * 8;

    auto stage = [&](int sel, int ko) {
        glds16(aS0 + ko, &As[sel][dof0]);
        glds16(aS1 + ko, &As[sel][dof1]);
        glds16(bS0 + ko, &Bs[sel][dof0]);
        glds16(bS1 + ko, &Bs[sel][dof1]);
    };
    auto compute = [&](int sel) {
        bf16x8 af[4], bfr[4];
#pragma unroll
        for (int m = 0; m < 4; ++m)
            af[m] = *(const bf16x8*)&As[sel][(arl + m * 16) * 32 + kk];
#pragma unroll
        for (int n = 0; n < 4; ++n)
            bfr[n] = *(const bf16x8*)&Bs[sel][(brl + n * 16) * 32 + kk];
#pragma unroll
        for (int m = 0; m < 4; ++m)
#pragma unroll
            for (int n = 0; n < 4; ++n)
                acc[m][n] = __builtin_amdgcn_mfma_f32_16x16x32_bf16(af[m], bfr[n], acc[m][n], 0, 0, 0);
    };

    int nk = K >> 5;                     // 10 (vW) or 8 (levels)
    stage(0, 0); stage(1, 32); stage(2, 64);
    for (int kt = 0; kt < nk - 3; ++kt) {
        asm volatile("s_waitcnt vmcnt(8)" ::: "memory");
        __builtin_amdgcn_s_barrier();
        __builtin_amdgcn_sched_barrier(0);
        compute(kt & 3);
        stage((kt + 3) & 3, (kt + 3) * 32);
    }
    asm volatile("s_waitcnt vmcnt(8)" ::: "memory");
    __builtin_amdgcn_s_barrier();
    __builtin_amdgcn_sched_barrier(0);
    compute((nk - 3) & 3);
    asm volatile("s_waitcnt vmcnt(4)" ::: "memory");
    __builtin_amdgcn_s_barrier();
    __builtin_amdgcn_sched_barrier(0);
    compute((nk - 2) & 3);
    asm volatile("s_waitcnt vmcnt(0)" ::: "memory");
    __builtin_amdgcn_s_barrier();
    __builtin_amdgcn_sched_barrier(0);
    compute((nk - 1) & 3);

    int crow = row0 + wr * 64 + (lane >> 4) * 4;
    int ccol = col0 + wc * 64 + (lane & 15);
#pragma unroll
    for (int m = 0; m < 4; ++m) {
#pragma unroll
        for (int n = 0; n < 4; ++n) {
#pragma unroll
            for (int j = 0; j < 4; ++j) {
                int r = crow + m * 16 + j;
                if (r < M) C[(long)r * N + ccol + n * 16] = f2bf(acc[m][n][j]);
            }
        }
    }

    if (FUSE) {
        // ---- release our g stores, count, last finisher updates this row-block ----
        __threadfence();                         // drain + make g stores device-visible
        __syncthreads();                         // all waves released
        if (t == 0)
            ((int*)As)[0] = (atomicAdd(&cnt[by], 1) == 5) ? 1 : 0;
        __syncthreads();
        if (((volatile int*)As)[0] == 0) return;
        __threadfence();                         // acquire: fresh g reads

        int pn = 1 << pnl;
        int j4 = lane * 4;
        const u16* g = C;
        for (int it = 0; it < 16; ++it) {
            int pi = by * 64 + it * 4 + w;       // level-local parent
            int bt = pi >> pnl, po = pi & (pn - 1);
            int pl = (pn - 1) + po;
            int gp  = bt * NND + pl;
            int gc1 = bt * NND + 2 * pl + 1, gc2 = gc1 + 1;
            long cc1 = (long)(2 * pi) * 768, cc2 = cc1 + 768;
            long vwb = (long)tok[gp] * 768;
            int d1 = dep[gc1] * 768, d2 = dep[gc2] * 768;
            u16x4 vf  = *(const u16x4*)(vW + vwb + j4);
            u16x4 vi  = *(const u16x4*)(vW + vwb + 256 + j4);
            u16x4 vu  = *(const u16x4*)(vW + vwb + 512 + j4);
            u16x4 gf1 = *(const u16x4*)(g + cc1 + j4);
            u16x4 gf2 = *(const u16x4*)(g + cc2 + j4);
            u16x4 gi1 = *(const u16x4*)(g + cc1 + 256 + j4);
            u16x4 gi2 = *(const u16x4*)(g + cc2 + 256 + j4);
            u16x4 gu1 = *(const u16x4*)(g + cc1 + 512 + j4);
            u16x4 gu2 = *(const u16x4*)(g + cc2 + 512 + j4);
            f32x4 qf1 = *(const f32x4*)(qD + d1 + j4);
            f32x4 qf2 = *(const f32x4*)(qD + d2 + j4);
            f32x4 qi1 = *(const f32x4*)(qD + d1 + 256 + j4);
            f32x4 qi2 = *(const f32x4*)(qD + d2 + 256 + j4);
            f32x4 qu1 = *(const f32x4*)(qD + d1 + 512 + j4);
            f32x4 qu2 = *(const f32x4*)(qD + d2 + 512 + j4);
            f32x4 bf_ = *(const f32x4*)(bias + j4);
            f32x4 bi_ = *(const f32x4*)(bias + 256 + j4);
            f32x4 bu_ = *(const f32x4*)(bias + 512 + j4);
            u16x4 h1v = *(const u16x4*)(h + (long)gc1 * HB + j4);
            u16x4 h2v = *(const u16x4*)(h + (long)gc2 * HB + j4);
            f32x4 res;
            u16x4 resb;
#pragma unroll
            for (int e = 0; e < 4; ++e) {
                float xf = bf2f(vf[e]) + bf_[e];
                float f1 = sigm(xf + bf2f(gf1[e]) + qf1[e]);
                float f2 = sigm(xf + bf2f(gf2[e]) + qf2[e]);
                float ii = bf2f(vi[e]) + bf2f(gi1[e]) + bf2f(gi2[e]) + qi1[e] + qi2[e] + bi_[e];
                float uu = bf2f(vu[e]) + bf2f(gu1[e]) + bf2f(gu2[e]) + qu1[e] + qu2[e] + bu_[e];
                float hn = tanhf(sigm(ii) * tanhf(uu) + f1 * bf2f(h1v[e]) + f2 * bf2f(h2v[e]));
                res[e] = hn;
                resb[e] = f2bf(hn);
            }
            if (out) *(f32x4*)(out + (long)pi * HB + j4) = res;   // lv6: pi == bt
            else     *(u16x4*)(h + (long)gp * HB + j4) = resb;
        }
    }
}

// ---------- leaves, vectorized: one wave per leaf, 4 j per lane ----------
__global__ __launch_bounds__(256) void k_leaf(const int* __restrict__ tok,
                                              const u16* __restrict__ vW,
                                              const float* __restrict__ qD,
                                              const float* __restrict__ b,
                                              u16* __restrict__ h) {
    int w = threadIdx.x >> 6, t = threadIdx.x & 63;
    int leaf = blockIdx.x * 4 + w;             // 0..32767
    int j = t * 4;
    int bt = leaf >> 6, li = leaf & 63;        // 64 leaves per tree
    int row = bt * NND + 63 + li;
    long vwb = (long)tok[row] * 768;
    u16x4 vi = *(const u16x4*)(vW + vwb + 256 + j);
    u16x4 vu = *(const u16x4*)(vW + vwb + 512 + j);
    f32x4 qi = *(const f32x4*)(qD + 9 * 768 + 256 + j);
    f32x4 qu = *(const f32x4*)(qD + 9 * 768 + 512 + j);
    f32x4 bi = *(const f32x4*)(b + 256 + j);
    f32x4 bu = *(const f32x4*)(b + 512 + j);
    u16x4 o;
#pragma unroll
    for (int e = 0; e < 4; ++e) {
        float ii = bf2f(vi[e]) + qi[e] + bi[e];
        float uu = bf2f(vu[e]) + qu[e] + bu[e];
        o[e] = f2bf(tanhf(sigm(ii) * tanhf(uu)));
    }
    *(u16x4*)(h + (long)row * HB + j) = o;
}

extern "C" void kernel_launch(void* const* d_in, const int* in_sizes, int n_in,
                              void* d_out, int out_size, void* d_ws, size_t ws_size,
                              hipStream_t stream) {
    const int*   tok = (const int*)d_in[0];
    const int*   dep = (const int*)d_in[1];
    const float* vec = (const float*)d_in[2];
    const float* q   = (const float*)d_in[3];
    const float* W   = (const float*)d_in[4];
    const float* U   = (const float*)d_in[5];
    const float* D   = (const float*)d_in[6];
    const float* b   = (const float*)d_in[7];

    char* ws = (char*)d_ws;
    size_t off = 0;
    auto alloc = [&](size_t bytes) {
        void* p = ws + off;
        off += (bytes + 255) & ~(size_t)255;
        return p;
    };
    float* qD  = (float*)alloc((size_t)QQ * 768 * 4);
    int*   cnt = (int*)alloc(504 * 4);
    u16*   vb  = (u16*)alloc((size_t)VV * KEP * 2);
    u16*   Wb  = (u16*)alloc((size_t)768 * KEP * 2);
    u16*   Ub  = (u16*)alloc((size_t)768 * HB * 2);
    u16*   vW  = (u16*)alloc((size_t)VV * 768 * 2);
    u16*   h   = (u16*)alloc((size_t)BT * NND * HB * 2);
    u16*   g   = (u16*)alloc((size_t)BT * 64 * 768 * 2);
    if (ws_size < off) return;  // ~177 MiB needed; zero output signals ws too small

    // 0) zero the row-block completion counters (re-done every launch/replay)
    hipMemsetAsync(cnt, 0, 504 * 4, stream);

    // 1) prep: vocab conv + W/U conv + qD (merged)
    k_prep<<<15871, 256, 0, stream>>>(vec, vb, W, U, q, D, Wb, Ub, qD);

    // 2) vW = (idx2vec @ W.T) bf16, vocab-wide
    k_gemm<false><<<dim3(6, (VV + 127) / 128), 256, 0, stream>>>(
        vb, Wb, vW, VV, KEP, -1, 0,
        nullptr, nullptr, nullptr, nullptr, nullptr, nullptr, nullptr, nullptr, 0);

    // 3) leaves
    k_leaf<<<BT * 64 / 4, 256, 0, stream>>>(tok, vW, qD, b, h);

    // 4) per-level GEMM with fused last-finisher update
    int coff = 0;
    for (int lv = 1; lv <= 6; ++lv) {
        int pnl = 6 - lv;
        int cnl = pnl + 1;
        int cstart = (1 << cnl) - 1;
        int ncT = BT << cnl;
        k_gemm<true><<<dim3(6, ncT / 128), 256, 0, stream>>>(
            h, Ub, g, ncT, HB, cnl, cstart,
            tok, dep, vW, qD, b, h,
            (lv == 6) ? (float*)d_out : nullptr,
            cnt + coff, pnl);
        coff += ncT / 128;
    }
}

// Round 17
// 208.819 us; speedup vs baseline: 4.0180x; 4.0180x over previous
//
#include <hip/hip_runtime.h>

typedef unsigned short u16;
typedef u16 u16x4 __attribute__((ext_vector_type(4)));
typedef u16 u16x8 __attribute__((ext_vector_type(8)));
typedef __bf16 bf16x8 __attribute__((ext_vector_type(8)));
typedef float f32x4 __attribute__((ext_vector_type(4)));

#define HB   256    // H
#define NND  127    // nodes per tree
#define BT   512    // trees (batch)
#define KE   300    // E
#define KEP  320    // E padded to 32-multiple
#define VV   50000  // vocab
#define QQ   10     // Q

#define AS1 __attribute__((address_space(1)))
#define AS3 __attribute__((address_space(3)))

__device__ __forceinline__ u16 f2bf(float f) {
    unsigned int u = __builtin_bit_cast(unsigned int, f);
    u += 0x7FFFu + ((u >> 16) & 1u);          // RNE
    return (u16)(u >> 16);
}
__device__ __forceinline__ float bf2f(u16 h) {
    unsigned int u = ((unsigned int)h) << 16;
    return __builtin_bit_cast(float, u);
}
__device__ __forceinline__ float sigm(float x) { return 1.f / (1.f + __expf(-x)); }

__device__ __forceinline__ void glds16(const u16* g, u16* l) {
    __builtin_amdgcn_global_load_lds((const AS1 void*)g, (AS3 void*)l, 16, 0, 0);
}

// ---------- merged prep: vocab conv (15625 blks), W (120), U (96), qD (30) ----------
__global__ __launch_bounds__(256) void k_prep(const float* __restrict__ vec,
                                              u16* __restrict__ vb,
                                              const float* __restrict__ W,
                                              const float* __restrict__ U,
                                              const float* __restrict__ q,
                                              const float* __restrict__ D,
                                              u16* __restrict__ Wb,
                                              u16* __restrict__ Ub,
                                              float* __restrict__ qD) {
    int blk = blockIdx.x;
    if (blk < 15625) {                     // vec: VV rows, K=300 -> Kp=320, u16x4 chunks
        long i = (long)blk * 256 + threadIdx.x;   // 4,000,000 chunks exactly
        int r = (int)(i / 80);
        int c = ((int)(i - (long)r * 80)) * 4;
        u16x4 o = {0, 0, 0, 0};
        if (c < KE) {
            f32x4 x = *(const f32x4*)(vec + (long)r * KE + c);
#pragma unroll
            for (int e = 0; e < 4; ++e) o[e] = f2bf(x[e]);
        }
        *(u16x4*)(vb + i * 4) = o;
    } else if (blk < 15745) {              // W: 768 rows, K=300 -> Kp=320 (40 chunks)
        int i = (blk - 15625) * 256 + threadIdx.x;
        int r = i / 40, c = (i - r * 40) * 8;
        const float* s = W + (long)r * KE + c;
        u16x8 o;
#pragma unroll
        for (int e = 0; e < 8; ++e) o[e] = (c + e < KE) ? f2bf(s[e]) : (u16)0;
        *(u16x8*)(Wb + (long)i * 8) = o;
    } else if (blk < 15841) {              // U: 768 rows, K=Kp=256 (32 chunks)
        int i = (blk - 15745) * 256 + threadIdx.x;
        int r = i / 32, c = (i - r * 32) * 8;
        const float* s = U + (long)r * HB + c;
        u16x8 o;
#pragma unroll
        for (int e = 0; e < 8; ++e) o[e] = f2bf(s[e]);
        *(u16x8*)(Ub + (long)i * 8) = o;
    } else {                               // qD[i] over QQ*768
        int i = (blk - 15841) * 256 + threadIdx.x;
        int qi = i / 768, col = i - qi * 768;
        const float* qr = q + qi * HB;
        const float* dr = D + col * HB;
        float s = 0.f;
        for (int k = 0; k < HB; ++k) s += qr[k] * dr[k];
        qD[i] = s;
    }
}

// ---------- bf16 NT GEMM: global_load_lds(16B), 128x128 tile ----------
// Depth-3 pipeline, 4 LDS buffers, counted vmcnt (T4) — best measured variant (R6), frozen.
// C[M,N] = A[M,K] * B[N,K]^T ; A,B bf16 row-major, K/32 = nk >= 4, N % 128 == 0.
// optional A-row map: global_row = (r>>cnlog2)*127 + cstart + (r & ((1<<cnlog2)-1))
template <bool STORE_BF16>
__global__ __launch_bounds__(256) void k_gemm(const u16* __restrict__ A,
                                              const u16* __restrict__ B,
                                              void* __restrict__ C,
                                              int M, int N, int K,
                                              int map_cnlog2, int map_cstart) {
    __shared__ u16 As[4][128 * 32];
    __shared__ u16 Bs[4][128 * 32];

    // bijective XCD-chunked swizzle (m204) on linear bid, x-inner
    int nwg = gridDim.x * gridDim.y;
    int orig = blockIdx.y * gridDim.x + blockIdx.x;
    int qq = nwg >> 3, rr = nwg & 7;
    int xcd = orig & 7, cidx = orig >> 3;
    int wg = (xcd < rr ? xcd * (qq + 1) : rr * (qq + 1) + (xcd - rr) * qq) + cidx;
    int bx = wg % gridDim.x, by = wg / gridDim.x;
    int row0 = by * 128, col0 = bx * 128;

    int t = threadIdx.x, lane = t & 63, w = t >> 6;
    int wr = w >> 1, wc = w & 1;

    // staging geometry: per wave-issue, 64 lanes x 16B = 16 rows x 32 u16
    int cof = (lane & 3) * 8;            // u16 col offset
    int rin = lane >> 2;                 // 0..15 row within issue
    int ar0 = row0 + w * 32 + rin;
    int ar1 = ar0 + 16;
    auto mapfn = [&](int r) {
        if (r > M - 1) r = M - 1;
        if (map_cnlog2 >= 0) {
            int bt = r >> map_cnlog2;
            int of = r & ((1 << map_cnlog2) - 1);
            r = bt * NND + map_cstart + of;
        }
        return r;
    };
    const u16* aS0 = A + (long)mapfn(ar0) * K + cof;
    const u16* aS1 = A + (long)mapfn(ar1) * K + cof;
    const u16* bS0 = B + (long)(col0 + w * 32 + rin) * K + cof;
    const u16* bS1 = bS0 + 16L * K;
    int dof0 = (w * 32) * 32;
    int dof1 = (w * 32 + 16) * 32;

    f32x4 acc[4][4];
#pragma unroll
    for (int m = 0; m < 4; ++m)
#pragma unroll
        for (int n = 0; n < 4; ++n) acc[m][n] = f32x4{0.f, 0.f, 0.f, 0.f};

    int arl = wr * 64 + (lane & 15);
    int brl = wc * 64 + (lane & 15);
    int kk = (lane >> 4) * 8;

    auto stage = [&](int sel, int ko) {
        glds16(aS0 + ko, &As[sel][dof0]);
        glds16(aS1 + ko, &As[sel][dof1]);
        glds16(bS0 + ko, &Bs[sel][dof0]);
        glds16(bS1 + ko, &Bs[sel][dof1]);
    };
    auto compute = [&](int sel) {
        bf16x8 af[4], bfr[4];
#pragma unroll
        for (int m = 0; m < 4; ++m)
            af[m] = *(const bf16x8*)&As[sel][(arl + m * 16) * 32 + kk];
#pragma unroll
        for (int n = 0; n < 4; ++n)
            bfr[n] = *(const bf16x8*)&Bs[sel][(brl + n * 16) * 32 + kk];
#pragma unroll
        for (int m = 0; m < 4; ++m)
#pragma unroll
            for (int n = 0; n < 4; ++n)
                acc[m][n] = __builtin_amdgcn_mfma_f32_16x16x32_bf16(af[m], bfr[n], acc[m][n], 0, 0, 0);
    };

    int nk = K >> 5;                     // 8 or 10 here (>= 4 required)
    stage(0, 0); stage(1, 32); stage(2, 64);     // 12 loads/wave in flight
    for (int kt = 0; kt < nk - 3; ++kt) {
        asm volatile("s_waitcnt vmcnt(8)" ::: "memory");
        __builtin_amdgcn_s_barrier();
        __builtin_amdgcn_sched_barrier(0);
        compute(kt & 3);
        stage((kt + 3) & 3, (kt + 3) * 32);
    }
    asm volatile("s_waitcnt vmcnt(8)" ::: "memory");
    __builtin_amdgcn_s_barrier();
    __builtin_amdgcn_sched_barrier(0);
    compute((nk - 3) & 3);
    asm volatile("s_waitcnt vmcnt(4)" ::: "memory");
    __builtin_amdgcn_s_barrier();
    __builtin_amdgcn_sched_barrier(0);
    compute((nk - 2) & 3);
    asm volatile("s_waitcnt vmcnt(0)" ::: "memory");
    __builtin_amdgcn_s_barrier();
    __builtin_amdgcn_sched_barrier(0);
    compute((nk - 1) & 3);

    int crow = row0 + wr * 64 + (lane >> 4) * 4;
    int ccol = col0 + wc * 64 + (lane & 15);
#pragma unroll
    for (int m = 0; m < 4; ++m) {
#pragma unroll
        for (int n = 0; n < 4; ++n) {
#pragma unroll
            for (int j = 0; j < 4; ++j) {
                int r = crow + m * 16 + j;
                int c = ccol + n * 16;
                if (r < M) {
                    if (STORE_BF16) ((u16*)C)[(long)r * N + c] = f2bf(acc[m][n][j]);
                    else            ((float*)C)[(long)r * N + c] = acc[m][n][j];
                }
            }
        }
    }
}

// ---------- leaves, vectorized: one wave per leaf, 4 j per lane ----------
__global__ __launch_bounds__(256) void k_leaf(const int* __restrict__ tok,
                                              const u16* __restrict__ vW,
                                              const float* __restrict__ qD,
                                              const float* __restrict__ b,
                                              u16* __restrict__ h) {
    int w = threadIdx.x >> 6, t = threadIdx.x & 63;
    int leaf = blockIdx.x * 4 + w;             // 0..32767
    int j = t * 4;
    int bt = leaf >> 6, li = leaf & 63;        // 64 leaves per tree
    int row = bt * NND + 63 + li;
    long vwb = (long)tok[row] * 768;
    u16x4 vi = *(const u16x4*)(vW + vwb + 256 + j);
    u16x4 vu = *(const u16x4*)(vW + vwb + 512 + j);
    f32x4 qi = *(const f32x4*)(qD + 9 * 768 + 256 + j);
    f32x4 qu = *(const f32x4*)(qD + 9 * 768 + 512 + j);
    f32x4 bi = *(const f32x4*)(b + 256 + j);
    f32x4 bu = *(const f32x4*)(b + 512 + j);
    u16x4 o;
#pragma unroll
    for (int e = 0; e < 4; ++e) {
        float ii = bf2f(vi[e]) + qi[e] + bi[e];
        float uu = bf2f(vu[e]) + qu[e] + bu[e];
        o[e] = f2bf(tanhf(sigm(ii) * tanhf(uu)));
    }
    *(u16x4*)(h + (long)row * HB + j) = o;
}

// ---------- per-level update, vectorized: one wave per parent, 4 j per lane ----------
// g row layout per child c (compact level order): [0:256]=f-part, [256:512]=i, [512:768]=u
__global__ __launch_bounds__(256) void k_update(const int* __restrict__ tok,
                                                const int* __restrict__ dep,
                                                const u16* __restrict__ vW,
                                                const float* __restrict__ qD,
                                                const float* __restrict__ b,
                                                const u16* __restrict__ g,
                                                u16* __restrict__ h,
                                                float* __restrict__ out,
                                                int pstart, int pnl) {
    int w = threadIdx.x >> 6, t = threadIdx.x & 63;
    int pi = blockIdx.x * 4 + w;
    int j = t * 4;
    int bt = pi >> pnl, po = pi & ((1 << pnl) - 1);
    int pl = pstart + po;
    int gp  = bt * NND + pl;
    int gc1 = bt * NND + 2 * pl + 1, gc2 = gc1 + 1;
    long cc1 = (long)((bt << (pnl + 1)) + 2 * po) * 768;  // g rows of the two children
    long cc2 = cc1 + 768;
    long vwb = (long)tok[gp] * 768;
    int d1 = dep[gc1] * 768, d2 = dep[gc2] * 768;
    u16x4 vf  = *(const u16x4*)(vW + vwb + j);
    u16x4 vi  = *(const u16x4*)(vW + vwb + 256 + j);
    u16x4 vu  = *(const u16x4*)(vW + vwb + 512 + j);
    u16x4 gf1 = *(const u16x4*)(g + cc1 + j);
    u16x4 gf2 = *(const u16x4*)(g + cc2 + j);
    u16x4 gi1 = *(const u16x4*)(g + cc1 + 256 + j);
    u16x4 gi2 = *(const u16x4*)(g + cc2 + 256 + j);
    u16x4 gu1 = *(const u16x4*)(g + cc1 + 512 + j);
    u16x4 gu2 = *(const u16x4*)(g + cc2 + 512 + j);
    f32x4 qf1 = *(const f32x4*)(qD + d1 + j);
    f32x4 qf2 = *(const f32x4*)(qD + d2 + j);
    f32x4 qi1 = *(const f32x4*)(qD + d1 + 256 + j);
    f32x4 qi2 = *(const f32x4*)(qD + d2 + 256 + j);
    f32x4 qu1 = *(const f32x4*)(qD + d1 + 512 + j);
    f32x4 qu2 = *(const f32x4*)(qD + d2 + 512 + j);
    f32x4 bf_ = *(const f32x4*)(b + j);
    f32x4 bi_ = *(const f32x4*)(b + 256 + j);
    f32x4 bu_ = *(const f32x4*)(b + 512 + j);
    u16x4 h1v = *(const u16x4*)(h + (long)gc1 * HB + j);
    u16x4 h2v = *(const u16x4*)(h + (long)gc2 * HB + j);
    f32x4 res;
    u16x4 resb;
#pragma unroll
    for (int e = 0; e < 4; ++e) {
        float xf = bf2f(vf[e]) + bf_[e];
        float f1 = sigm(xf + bf2f(gf1[e]) + qf1[e]);
        float f2 = sigm(xf + bf2f(gf2[e]) + qf2[e]);
        float ii = bf2f(vi[e]) + bf2f(gi1[e]) + bf2f(gi2[e]) + qi1[e] + qi2[e] + bi_[e];
        float uu = bf2f(vu[e]) + bf2f(gu1[e]) + bf2f(gu2[e]) + qu1[e] + qu2[e] + bu_[e];
        float hn = tanhf(sigm(ii) * tanhf(uu) + f1 * bf2f(h1v[e]) + f2 * bf2f(h2v[e]));
        res[e] = hn;
        resb[e] = f2bf(hn);
    }
    if (out) *(f32x4*)(out + (long)pi * HB + j) = res;     // lv6: pi == bt, fp32 output
    else     *(u16x4*)(h + (long)gp * HB + j) = resb;
}

extern "C" void kernel_launch(void* const* d_in, const int* in_sizes, int n_in,
                              void* d_out, int out_size, void* d_ws, size_t ws_size,
                              hipStream_t stream) {
    const int*   tok = (const int*)d_in[0];
    const int*   dep = (const int*)d_in[1];
    const float* vec = (const float*)d_in[2];
    const float* q   = (const float*)d_in[3];
    const float* W   = (const float*)d_in[4];
    const float* U   = (const float*)d_in[5];
    const float* D   = (const float*)d_in[6];
    const float* b   = (const float*)d_in[7];

    char* ws = (char*)d_ws;
    size_t off = 0;
    auto alloc = [&](size_t bytes) {
        void* p = ws + off;
        off += (bytes + 255) & ~(size_t)255;
        return p;
    };
    float* qD = (float*)alloc((size_t)QQ * 768 * 4);
    u16*   vb = (u16*)alloc((size_t)VV * KEP * 2);
    u16*   Wb = (u16*)alloc((size_t)768 * KEP * 2);
    u16*   Ub = (u16*)alloc((size_t)768 * HB * 2);
    u16*   vW = (u16*)alloc((size_t)VV * 768 * 2);
    u16*   h  = (u16*)alloc((size_t)BT * NND * HB * 2);
    u16*   g  = (u16*)alloc((size_t)BT * 64 * 768 * 2);
    if (ws_size < off) return;  // ~177 MiB needed; zero output signals ws too small

    // 1) prep: vocab conv + W/U conv + qD (merged, one dispatch)
    k_prep<<<15871, 256, 0, stream>>>(vec, vb, W, U, q, D, Wb, Ub, qD);

    // 2) vW = (idx2vec @ W.T) as bf16, vocab-wide
    k_gemm<true><<<dim3(6, (VV + 127) / 128), 256, 0, stream>>>(
        vb, Wb, vW, VV, 768, KEP, -1, 0);

    // 3) leaves
    k_leaf<<<BT * 64 / 4, 256, 0, stream>>>(tok, vW, qD, b, h);

    // 4) per-level split pipeline (measured best): g GEMM + update
    for (int lv = 1; lv <= 6; ++lv) {
        int pnl = 6 - lv;              // log2(parents per tree)
        int pn = 1 << pnl;
        int cnl = pnl + 1;             // log2(children per tree)
        int cstart = (1 << cnl) - 1;
        int npT = BT * pn, ncT = BT * (1 << cnl);
        k_gemm<true><<<dim3(6, ncT / 128), 256, 0, stream>>>(
            h, Ub, g, ncT, 768, HB, cnl, cstart);
        k_update<<<npT / 4, 256, 0, stream>>>(tok, dep, vW, qD, b, g, h,
                                              (lv == 6) ? (float*)d_out : nullptr,
                                              pn - 1, pnl);
    }
}